// Round 9
// baseline (42.975 us; speedup 1.0000x reference)
//
#include <hip/hip_runtime.h>

#define T_LEN 768
#define TC 32                 // timesteps per chunk
#define NCH (T_LEN / TC)      // 24 chunks
#define RPB 64                // rows per block (consumer: 1 row per lane)
#define R1S 36                // r1 plane row stride (floats), 16B-aligned
#define OS  65                // lds_o stride (odd -> conflict-free writes)

struct Params { const float* p[27]; };

__device__ __forceinline__ float ex2(float x){ float r; asm("v_exp_f32 %0, %1":"=v"(r):"v"(x)); return r; }
__device__ __forceinline__ float frcp(float x){ return __builtin_amdgcn_rcpf(x); }
__device__ __forceinline__ float psig(float v, float k, float c){
    return frcp(1.0f + ex2(__builtin_fmaf(-k, v, c)));
}

// Block = 192 threads: wave0 = serial consumer (1 row/lane, BOTH channels in
// registers -> cross-coupling is a register read, NO dpp on the chain),
// waves 1-2 = producers (global loads, input sigmoids, output drains).
//
// Consumer SHARE state per channel q in {x,y}: sg (sigma), h1,h2,h3 (synapse
// drives, affine in W, updated incrementally), cfac = -ln2*sg(1-sg),
// hd2 = cfac*(ln2*sg - ln2/2)  (refreshed every 4 steps), dl2p lagged dl^2.
// Per step (carried cycle sg -> dl -> sg', 2 fma deps; x/y fully ILP):
//   dlx  = fma(sgy, h3x, fma(sgx, h2x, p1x))      p1x = ra[t]*h1x
//   sgx' = fma(cfacx, dlx, fma(hd2x, dl2px, sgx))
//   h1x..h3x += mG*dlx ; p1x = ra[t+1]*h1x ; cfacx refresh ; (sym. for y)
//   store h2x (affine proxy of v_x; producer maps h2->v on drain)
// Exact exp2+rcp re-anchor per chunk caps drift (W recovered from h2).
__global__ __launch_bounds__(192, 1) void cell_kernel(Params P, float* __restrict__ out) {
    __shared__ float r1a[2][RPB][R1S];    // [buf][row][t]  sigma_ax(a)
    __shared__ float r1b[2][RPB][R1S];    // [buf][row][t]  sigma_by(b)
    __shared__ float lds_o[2][TC][OS];    // [buf][t][row]  h2x proxy

    const int tid = (int)threadIdx.x;
    const int r0  = (int)blockIdx.x * RPB;
    const int wv  = tid >> 6;             // 0 = consumer, 1..2 = producers
    const int l   = tid & 63;

    const float* __restrict__ inp = P.p[0];
    const float capx = P.p[1][0], capy = P.p[2][0];
    const float g_ax = P.p[3][0],  m_ax = P.p[4][0],  s_ax = P.p[5][0],  q_ax = P.p[6][0];
    const float g_by = P.p[7][0],  m_by = P.p[8][0],  s_by = P.p[9][0],  q_by = P.p[10][0];
    const float g_xx = P.p[11][0], m_xx = P.p[12][0], s_xx = P.p[13][0], q_xx = P.p[14][0];
    const float g_xy = P.p[15][0], m_xy = P.p[16][0], s_xy = P.p[17][0], q_xy = P.p[18][0];
    const float g_yx = P.p[19][0], m_yx = P.p[20][0], s_yx = P.p[21][0], q_yx = P.p[22][0];
    const float g_yy = P.p[23][0], m_yy = P.p[24][0], s_yy = P.p[25][0], q_yy = P.p[26][0];

    const float icx = 1.0f / capx, icy = 1.0f / capy;
    const float L2E  = 1.44269504088896340736f;
    const float LN2  = 0.69314718056f;
    const float mLN2 = -0.69314718056f;
    const float mHLN2 = -0.34657359028f;     // -ln2/2

    // input-synapse sigmoids (producers)
    const float k1x = s_ax * L2E, c1x = k1x * m_ax;
    const float k1y = s_by * L2E, c1y = k1y * m_by;

    // per-channel recurrence constants (wave-uniform; no lane selects)
    const float k2x = s_xx * L2E, c2x = k2x * m_xx;
    const float k2y = s_yy * L2E, c2y = k2y * m_yy;
    const float A1x = g_ax * q_ax * icx, G1x = g_ax * icx;
    const float A2x = g_xx * q_xx * icx, G2x = g_xx * icx;
    const float A3x = g_yx * q_yx * icx, G3x = g_yx * icx;   // cross-IN (pre=y)
    const float A1y = g_by * q_by * icy, G1y = g_by * icy;
    const float A2y = g_yy * q_yy * icy, G2y = g_yy * icy;
    const float A3y = g_xy * q_xy * icy, G3y = g_xy * icy;   // cross-IN (pre=x)

    // W-space: h_i = fma(mG_i, W, R_i), R_i = G_i*c2 - k2*A_i
    const float R1x = __builtin_fmaf(G1x, c2x, -k2x * A1x);
    const float R2x = __builtin_fmaf(G2x, c2x, -k2x * A2x);
    const float R3x = __builtin_fmaf(G3x, c2x, -k2x * A3x);
    const float R1y = __builtin_fmaf(G1y, c2y, -k2y * A1y);
    const float R2y = __builtin_fmaf(G2y, c2y, -k2y * A2y);
    const float R3y = __builtin_fmaf(G3y, c2y, -k2y * A3y);
    const float mG1x = -G1x, mG2x = -G2x, mG3x = -G3x;
    const float mG1y = -G1y, mG2y = -G2y, mG3y = -G3y;
    const float inv_mG2x = 1.0f / mG2x, inv_mG2y = 1.0f / mG2y;

    const bool share = (s_yx == s_yy) && (m_yx == m_yy) &&
                       (s_xy == s_xx) && (m_xy == m_xx) &&
                       (s_xx != 0.0f) && (s_yy != 0.0f) &&
                       (g_xx != 0.0f) && (g_yy != 0.0f);

    // drain map: v_x = fma(stored, cv1, cv0); share stores h2x, else stores v_x
    const float cv1 = share ? 1.0f / (G2x * k2x) : 1.0f;
    const float cv0 = share ? (c2x / k2x - R2x / (G2x * k2x)) : 0.0f;

    // general (non-share) fallback sigmoids
    const float kyx = s_yx * L2E, cyx = kyx * m_yx;
    const float kxy = s_xy * L2E, cxy = kxy * m_xy;

    const float4* __restrict__ in4 = (const float4*)inp;     // row stride 384 f4

    if (wv != 0) {
        // ================= PRODUCERS =================
        const int p = wv - 1;                                // 0 or 1
        auto SIGW = [&](float4 (&pin)[8], int buf) {
            #pragma unroll
            for (int k = 0; k < 8; ++k) { int idx = l + 64*(8*p + k);
                int r_ = idx >> 4, q = idx & 15;
                r1a[buf][r_][2*q]     = psig(pin[k].x, k1x, c1x);
                r1b[buf][r_][2*q]     = psig(pin[k].y, k1y, c1y);
                r1a[buf][r_][2*q + 1] = psig(pin[k].z, k1x, c1x);
                r1b[buf][r_][2*q + 1] = psig(pin[k].w, k1y, c1y); }
        };
        auto LOADP = [&](float4 (&pin)[8], int c) {
            #pragma unroll
            for (int k = 0; k < 8; ++k) { int idx = l + 64*(8*p + k);
                int r_ = idx >> 4, q = idx & 15;
                pin[k] = in4[(size_t)(r0 + r_) * 384 + c * 16 + q]; }
        };
        auto DRAIN = [&](int c) {      // chunk c outputs (buf c&1), h2->v map
            const int buf = c & 1;
            #pragma unroll
            for (int k = 0; k < 4; ++k) { int f = l + 64*(4*p + k);
                int r_ = f >> 3, pq = f & 7;
                float4 o;
                o.x = __builtin_fmaf(lds_o[buf][4*pq + 0][r_], cv1, cv0);
                o.y = __builtin_fmaf(lds_o[buf][4*pq + 1][r_], cv1, cv0);
                o.z = __builtin_fmaf(lds_o[buf][4*pq + 2][r_], cv1, cv0);
                o.w = __builtin_fmaf(lds_o[buf][4*pq + 3][r_], cv1, cv0);
                *(float4*)&out[(size_t)(r0 + r_) * T_LEN + c * TC + 4*pq] = o; }
        };

        float4 pin[8];
        LOADP(pin, 0);
        SIGW(pin, 0);
        __syncthreads();
        for (int c = 0; c < NCH; ++c) {
            if (c + 1 < NCH) LOADP(pin, c + 1);      // issue loads first
            if (c >= 1) DRAIN(c - 1);                // drain under load latency
            if (c + 1 < NCH) SIGW(pin, (c + 1) & 1); // sigmoids for next chunk
            __syncthreads();
        }
        DRAIN(NCH - 1);
    } else {
        // ================= CONSUMER (wave 0) =================
        // state init at v=0 -> W = c2
        float h1x = __builtin_fmaf(mG1x, c2x, R1x);
        float h2x = __builtin_fmaf(mG2x, c2x, R2x);
        float h3x = __builtin_fmaf(mG3x, c2x, R3x);
        float h1y = __builtin_fmaf(mG1y, c2y, R1y);
        float h2y = __builtin_fmaf(mG2y, c2y, R2y);
        float h3y = __builtin_fmaf(mG3y, c2y, R3y);
        float vx = 0.0f, vy = 0.0f;                  // general path

        __syncthreads();
        for (int c = 0; c < NCH; ++c) {
            const int buf = c & 1;
            float ra_[TC], rb_[TC];
            #pragma unroll
            for (int j = 0; j < 8; ++j) {
                float4 va4 = *(const float4*)&r1a[buf][l][4*j];
                float4 vb4 = *(const float4*)&r1b[buf][l][4*j];
                ra_[4*j] = va4.x; ra_[4*j+1] = va4.y; ra_[4*j+2] = va4.z; ra_[4*j+3] = va4.w;
                rb_[4*j] = vb4.x; rb_[4*j+1] = vb4.y; rb_[4*j+2] = vb4.z; rb_[4*j+3] = vb4.w;
            }
            if (share) {
                // exact anchor: recover W from h2 (exactly linear)
                float Wx = (h2x - R2x) * inv_mG2x;
                float Wy = (h2y - R2y) * inv_mG2y;
                float sgx = frcp(1.0f + ex2(Wx));
                float sgy = frcp(1.0f + ex2(Wy));
                float t1x = __builtin_fmaf(-sgx, sgx, sgx);
                float t1y = __builtin_fmaf(-sgy, sgy, sgy);
                float cfx = mLN2 * t1x, cfy = mLN2 * t1y;
                float hd2x = cfx * __builtin_fmaf(LN2, sgx, mHLN2);
                float hd2y = cfy * __builtin_fmaf(LN2, sgy, mHLN2);
                float dl2px = 0.0f, dl2py = 0.0f;
                float p1x = ra_[0] * h1x, p1y = rb_[0] * h1y;
                #pragma unroll
                for (int t = 0; t < TC; ++t) {
                    float sx = __builtin_fmaf(sgx, h2x, p1x);
                    float dlx = __builtin_fmaf(sgy, h3x, sx);       // cross = reg read
                    float sy = __builtin_fmaf(sgy, h2y, p1y);
                    float dly = __builtin_fmaf(sgx, h3y, sy);
                    float inx = __builtin_fmaf(hd2x, dl2px, sgx);   // lagged 2nd order
                    float iny = __builtin_fmaf(hd2y, dl2py, sgy);
                    float sgxn = __builtin_fmaf(cfx, dlx, inx);
                    float sgyn = __builtin_fmaf(cfy, dly, iny);
                    dl2px = dlx * dlx;  dl2py = dly * dly;
                    h1x = __builtin_fmaf(mG1x, dlx, h1x);
                    h2x = __builtin_fmaf(mG2x, dlx, h2x);
                    h3x = __builtin_fmaf(mG3x, dlx, h3x);
                    h1y = __builtin_fmaf(mG1y, dly, h1y);
                    h2y = __builtin_fmaf(mG2y, dly, h2y);
                    h3y = __builtin_fmaf(mG3y, dly, h3y);
                    if (t + 1 < TC) { p1x = ra_[t+1] * h1x; p1y = rb_[t+1] * h1y; }
                    t1x = __builtin_fmaf(-sgxn, sgxn, sgxn);
                    t1y = __builtin_fmaf(-sgyn, sgyn, sgyn);
                    cfx = mLN2 * t1x;  cfy = mLN2 * t1y;
                    if ((t & 3) == 3) {                             // slow-varying
                        hd2x = cfx * __builtin_fmaf(LN2, sgxn, mHLN2);
                        hd2y = cfy * __builtin_fmaf(LN2, sgyn, mHLN2);
                    }
                    lds_o[buf][t][l] = h2x;                         // v_x proxy
                    sgx = sgxn;  sgy = sgyn;
                }
            } else {
                #pragma unroll
                for (int t = 0; t < TC; ++t) {
                    float s2x = psig(vx, k2x, c2x);
                    float s2y = psig(vy, k2y, c2y);
                    float syx = psig(vy, kyx, cyx);
                    float sxy = psig(vx, kxy, cxy);
                    float u1x = __builtin_fmaf(-vx, G1x, A1x);
                    float u2x = __builtin_fmaf(-vx, G2x, A2x);
                    float u3x = __builtin_fmaf(-vx, G3x, A3x);
                    float u1y = __builtin_fmaf(-vy, G1y, A1y);
                    float u2y = __builtin_fmaf(-vy, G2y, A2y);
                    float u3y = __builtin_fmaf(-vy, G3y, A3y);
                    float nvx = __builtin_fmaf(syx, u3x,
                                __builtin_fmaf(s2x, u2x, __builtin_fmaf(ra_[t], u1x, vx)));
                    float nvy = __builtin_fmaf(sxy, u3y,
                                __builtin_fmaf(s2y, u2y, __builtin_fmaf(rb_[t], u1y, vy)));
                    vx = nvx; vy = nvy;
                    lds_o[buf][t][l] = vx;                          // cv=(1,0)
                }
            }
            __syncthreads();
        }
    }
}

extern "C" void kernel_launch(void* const* d_in, const int* in_sizes, int n_in,
                              void* d_out, int out_size, void* d_ws, size_t ws_size,
                              hipStream_t stream) {
    (void)d_ws; (void)ws_size; (void)out_size; (void)n_in;
    Params P;
    for (int i = 0; i < 27; ++i) P.p[i] = (const float*)d_in[i];
    float* out = (float*)d_out;
    const int B = in_sizes[0] / (T_LEN * 2);   // 16384
    dim3 grid(B / RPB);                        // 256 blocks x 192 threads (3 waves)
    cell_kernel<<<grid, dim3(192), 0, stream>>>(P, out);
}

// Round 10
// 34.920 us; speedup vs baseline: 1.2307x; 1.2307x over previous
//
#include <hip/hip_runtime.h>

#define T_LEN 768
#define TC 32                 // timesteps per chunk
#define NCH (T_LEN / TC)      // 24 chunks
#define RPB 32                // rows per block
#define RS  66                // r1buf stride: [t][lane], bank-spread reads
#define OS  66                // lds_o stride: [t][lane], conflict-free writes

struct Params { const float* p[27]; };

__device__ __forceinline__ float ex2(float x){ float r; asm("v_exp_f32 %0, %1":"=v"(r):"v"(x)); return r; }
__device__ __forceinline__ float frcp(float x){ return __builtin_amdgcn_rcpf(x); }
__device__ __forceinline__ float dpp_xor1(float x){
    // lane <-> lane^1 swap, quad_perm [1,0,3,2]; pure VALU
    return __int_as_float(__builtin_amdgcn_mov_dpp(__float_as_int(x),0xB1,0xF,0xF,true));
}
__device__ __forceinline__ float psig(float v, float k, float c){
    return frcp(1.0f + ex2(__builtin_fmaf(-k, v, c)));
}

// Block = 192 threads: wave0 = serial consumer (2 lanes/row x 32 rows,
// R8's proven trans-free chain), waves 1-2 = producers, each doing HALF of
// {global loads, input sigmoids, output drains}. Loads pipelined 2 chunks
// ahead in registers so the vmcnt wait is hidden under a full chunk.
__global__ __launch_bounds__(192, 1) void cell_kernel(Params P, float* __restrict__ out) {
    __shared__ float r1buf[2][TC][RS];    // [buf][t][consumer-lane] input sigmas
    __shared__ float lds_o[2][TC][OS];    // [buf][t][consumer-lane] output proxy

    const int tid = (int)threadIdx.x;
    const int r0  = (int)blockIdx.x * RPB;
    const int wv  = tid >> 6;             // 0 = consumer, 1..2 = producers
    const int l   = tid & 63;

    const float* __restrict__ inp = P.p[0];
    const float capx = P.p[1][0], capy = P.p[2][0];
    const float g_ax = P.p[3][0],  m_ax = P.p[4][0],  s_ax = P.p[5][0],  q_ax = P.p[6][0];
    const float g_by = P.p[7][0],  m_by = P.p[8][0],  s_by = P.p[9][0],  q_by = P.p[10][0];
    const float g_xx = P.p[11][0], m_xx = P.p[12][0], s_xx = P.p[13][0], q_xx = P.p[14][0];
    const float g_xy = P.p[15][0], m_xy = P.p[16][0], s_xy = P.p[17][0], q_xy = P.p[18][0];
    const float g_yx = P.p[19][0], m_yx = P.p[20][0], s_yx = P.p[21][0], q_yx = P.p[22][0];
    const float g_yy = P.p[23][0], m_yy = P.p[24][0], s_yy = P.p[25][0], q_yy = P.p[26][0];

    const float icx = 1.0f / capx, icy = 1.0f / capy;
    const float L2E  = 1.44269504088896340736f;
    const float LN2  = 0.69314718056f;
    const float mLN2 = -0.69314718056f;
    const float mHLN2 = -0.34657359028f;      // -ln2/2

    // input-synapse sigmoids (producers)
    const float k1x = s_ax * L2E, c1x = k1x * m_ax;
    const float k1y = s_by * L2E, c1y = k1y * m_by;

    const bool share = (s_yx == s_yy) && (m_yx == m_yy) &&
                       (s_xy == s_xx) && (m_xy == m_xx) &&
                       (s_xx != 0.0f) && (s_yy != 0.0f) &&
                       (g_xx != 0.0f) && (g_yy != 0.0f);

    // drain map (producers): v_x = fma(stored, cv1, cv0)
    const float k2xp = s_xx * L2E, c2xp = k2xp * m_xx;
    const float G2xp = g_xx * icx;
    const float A2xp = g_xx * q_xx * icx;
    const float R2xp = __builtin_fmaf(G2xp, c2xp, -k2xp * A2xp);
    const float cv1 = share ? 1.0f / (G2xp * k2xp) : 1.0f;
    const float cv0 = share ? (c2xp / k2xp - R2xp * (1.0f / (G2xp * k2xp))) : 0.0f;

    const float4* __restrict__ in4 = (const float4*)inp;     // row stride 384 f4

    if (wv != 0) {
        // ================= PRODUCERS (waves 1-2) =================
        const int p = wv - 1;                                // 0 or 1
        float4 pinA[4], pinB[4];

        auto LOADP = [&](float4 (&pin)[4], int c) {
            #pragma unroll
            for (int k = 0; k < 4; ++k) { int idx = l + 64*(p*4 + k);
                int r_ = idx >> 4, q = idx & 15;
                pin[k] = in4[(size_t)(r0 + r_) * 384 + c * 16 + q]; }
        };
        auto SIGW = [&](float4 (&pin)[4], int buf) {
            #pragma unroll
            for (int k = 0; k < 4; ++k) { int idx = l + 64*(p*4 + k);
                int r_ = idx >> 4, q = idx & 15;
                float2 w0, w1;                               // [t][lane] layout
                w0.x = psig(pin[k].x, k1x, c1x);             // a_{2q}  -> lane 2r
                w0.y = psig(pin[k].y, k1y, c1y);             // b_{2q}  -> lane 2r+1
                w1.x = psig(pin[k].z, k1x, c1x);             // a_{2q+1}
                w1.y = psig(pin[k].w, k1y, c1y);             // b_{2q+1}
                *(float2*)&r1buf[buf][2*q]    [2*r_] = w0;   // b64, <=4-way
                *(float2*)&r1buf[buf][2*q + 1][2*r_] = w1; }
        };
        auto DRAIN = [&](int c) {       // chunk c (buf c&1), h2 -> v map
            const int buf = c & 1;
            #pragma unroll
            for (int k = 0; k < 2; ++k) { int f = l + 64*(p*2 + k);
                int r_ = f >> 3, pq = f & 7;
                float4 o;
                o.x = __builtin_fmaf(lds_o[buf][4*pq + 0][2*r_], cv1, cv0);
                o.y = __builtin_fmaf(lds_o[buf][4*pq + 1][2*r_], cv1, cv0);
                o.z = __builtin_fmaf(lds_o[buf][4*pq + 2][2*r_], cv1, cv0);
                o.w = __builtin_fmaf(lds_o[buf][4*pq + 3][2*r_], cv1, cv0);
                *(float4*)&out[(size_t)(r0 + r_) * T_LEN + c * TC + 4*pq] = o; }
        };

        LOADP(pinA, 0);
        LOADP(pinB, 1);
        SIGW(pinA, 0);                   // chunk 0 sigmas ready
        __syncthreads();
        for (int c = 0; c < NCH; ++c) {
            // refill the slot freed by last iteration's SIGW (chunk c+2)
            if (c + 2 < NCH) { if ((c & 1) == 0) LOADP(pinA, c + 2);
                               else              LOADP(pinB, c + 2); }
            if (c >= 1) DRAIN(c - 1);    // drain under load latency
            if (c + 1 < NCH) {           // sigmas for chunk c+1 (loaded @ c-1)
                if ((c & 1) == 0) SIGW(pinB, (c + 1) & 1);
                else              SIGW(pinA, (c + 1) & 1);
            }
            __syncthreads();
        }
        DRAIN(NCH - 1);
    } else {
        // ================= CONSUMER (wave 0) — R8's proven core =================
        __builtin_amdgcn_s_setprio(1);   // favor the serial wave on its SIMD

        const bool isX = (l & 1) == 0;
        const float k2r = (isX ? s_xx : s_yy) * L2E;
        const float c2r = k2r * (isX ? m_xx : m_yy);
        const float k3r = (isX ? s_xy : s_yx) * L2E;         // cross-OUT (general)
        const float c3r = k3r * (isX ? m_xy : m_yx);
        const float icr = isX ? icx : icy;
        const float A1r = (isX ? g_ax * q_ax : g_by * q_by) * icr, G1r = (isX ? g_ax : g_by) * icr;
        const float A2r = (isX ? g_xx * q_xx : g_yy * q_yy) * icr, G2r = (isX ? g_xx : g_yy) * icr;
        const float A3r = (isX ? g_yx * q_yx : g_xy * q_xy) * icr, G3r = (isX ? g_yx : g_xy) * icr;

        const float R1 = __builtin_fmaf(G1r, c2r, -k2r * A1r);
        const float R2 = __builtin_fmaf(G2r, c2r, -k2r * A2r);
        const float R3 = __builtin_fmaf(G3r, c2r, -k2r * A3r);
        const float mG1 = -G1r, mG2 = -G2r, mG3 = -G3r;
        const float inv_mG2 = 1.0f / mG2;

        float h1 = __builtin_fmaf(mG1, c2r, R1);
        float h2 = __builtin_fmaf(mG2, c2r, R2);
        float h3 = __builtin_fmaf(mG3, c2r, R3);
        float v = 0.0f;                  // general path

        __syncthreads();
        for (int c = 0; c < NCH; ++c) {
            const int buf = c & 1;
            float rr[TC];                // conflict-free b32 reads ([t][l])
            #pragma unroll
            for (int t = 0; t < TC; ++t) rr[t] = r1buf[buf][t][l];

            if (share) {
                float Wr  = (h2 - R2) * inv_mG2;             // exact anchor
                float E   = ex2(Wr);
                float sg  = frcp(1.0f + E);
                float t1  = __builtin_fmaf(-sg, sg, sg);
                float cfac = mLN2 * t1;
                float w2  = __builtin_fmaf(LN2, sg, mHLN2);
                float hd2 = cfac * w2;
                float dl2p = 0.0f;
                float p1 = rr[0] * h1;
                #pragma unroll
                for (int t = 0; t < TC; ++t) {
                    float rp   = dpp_xor1(sg);               // partner sigma
                    float s2mW = __builtin_fmaf(sg, h2, p1);
                    float dl   = __builtin_fmaf(rp, h3, s2mW);
                    float inner = __builtin_fmaf(hd2, dl2p, sg);
                    float sgn  = __builtin_fmaf(cfac, dl, inner);
                    dl2p = dl * dl;
                    h1 = __builtin_fmaf(mG1, dl, h1);
                    h2 = __builtin_fmaf(mG2, dl, h2);
                    h3 = __builtin_fmaf(mG3, dl, h3);
                    if (t + 1 < TC) p1 = rr[t + 1] * h1;
                    t1   = __builtin_fmaf(-sgn, sgn, sgn);
                    cfac = mLN2 * t1;
                    if ((t & 3) == 3) {                      // slow-varying refresh
                        w2  = __builtin_fmaf(LN2, sgn, mHLN2);
                        hd2 = cfac * w2;
                    }
                    lds_o[buf][t][l] = h2;                   // v proxy (affine)
                    sg = sgn;
                }
            } else {
                #pragma unroll
                for (int t = 0; t < TC; ++t) {
                    float s2 = psig(v, k2r, c2r);
                    float s3 = psig(v, k3r, c3r);
                    float rp = dpp_xor1(s3);
                    float u1 = __builtin_fmaf(-v, G1r, A1r);
                    float u2 = __builtin_fmaf(-v, G2r, A2r);
                    float u3 = __builtin_fmaf(-v, G3r, A3r);
                    v = __builtin_fmaf(rp, u3,
                        __builtin_fmaf(s2, u2,
                        __builtin_fmaf(rr[t], u1, v)));
                    lds_o[buf][t][l] = v;                    // cv=(1,0)
                }
            }
            __syncthreads();
        }
    }
}

extern "C" void kernel_launch(void* const* d_in, const int* in_sizes, int n_in,
                              void* d_out, int out_size, void* d_ws, size_t ws_size,
                              hipStream_t stream) {
    (void)d_ws; (void)ws_size; (void)out_size; (void)n_in;
    Params P;
    for (int i = 0; i < 27; ++i) P.p[i] = (const float*)d_in[i];
    float* out = (float*)d_out;
    const int B = in_sizes[0] / (T_LEN * 2);   // 16384
    dim3 grid(B / RPB);                        // 512 blocks x 192 threads (3 waves)
    cell_kernel<<<grid, dim3(192), 0, stream>>>(P, out);
}